// Round 11
// baseline (275.518 us; speedup 1.0000x reference)
//
#include <hip/hip_runtime.h>
#include <stdint.h>

// B=2, T=2048, D_MODEL=1536, H=16, hd=96, n_trip=32. qkv row = 4608, rows = 4096.

typedef unsigned short u16;
typedef unsigned int u32;
typedef __attribute__((ext_vector_type(8))) __bf16 bf16x8;   // MFMA A/B frag
typedef __attribute__((ext_vector_type(4))) float f32x4;     // MFMA C/D frag

#define DEV static __device__ __forceinline__

DEV u16 f2bf(float f) {
  u32 u = __float_as_uint(f);
  return (u16)((u + 0x7fffu + ((u >> 16) & 1u)) >> 16);  // RNE
}
DEV float bf2f(u16 h) { return __uint_as_float(((u32)h) << 16); }
DEV u32 cvtpk(float lo, float hi) {  // packed f32->bf16 pair (lo->bits[15:0])
  u32 r;
  asm("v_cvt_pk_bf16_f32 %0, %1, %2" : "=v"(r) : "v"(lo), "v"(hi));
  return r;
}
DEV float exp2f_fast(float x) {
  float r;
  asm("v_exp_f32 %0, %1" : "=v"(r) : "v"(x));
  return r;
}
DEV float max3f(float a, float b, float c) { return fmaxf(fmaxf(a, b), c); }

// async global->LDS, 16B/lane. LDS dest = wave-uniform base + lane*16.
DEV void gload16(u16* lds_dst, const u16* gsrc) {
  __builtin_amdgcn_global_load_lds(
      (const __attribute__((address_space(1))) void*)gsrc,
      (__attribute__((address_space(3))) void*)lds_dst, 16, 0, 0);
}

// ---------------------------------------------------------------- cvt f32->bf16 x3
__global__ __launch_bounds__(256) void cvt3(const float* __restrict__ a, u16* __restrict__ ao, int na4,
                                            const float* __restrict__ b, u16* __restrict__ bo, int nb4,
                                            const float* __restrict__ c, u16* __restrict__ co, int nc4) {
  int i = blockIdx.x * 256 + threadIdx.x;
  const float* src;
  u16* dst;
  if (i < na4) { src = a; dst = ao; }
  else if (i < na4 + nb4) { i -= na4; src = b; dst = bo; }
  else if (i < na4 + nb4 + nc4) { i -= na4 + nb4; src = c; dst = co; }
  else return;
  float4 v = reinterpret_cast<const float4*>(src)[i];
  ushort4 o;
  o.x = f2bf(v.x); o.y = f2bf(v.y); o.z = f2bf(v.z); o.w = f2bf(v.w);
  reinterpret_cast<ushort4*>(dst)[i] = o;
}

// ---------------------------------------------------------------- GEMM (128x192)
// VERIFIED config (66.5 us, MfmaUtil 35%, VGPR 56): BM=128, BN=192, BK=64,
// 8 waves (512 thr) as 2M x 4N -> wave tile 64x48. LDS 80 KiB dbuf -> 2
// blocks/CU = 16 waves/CU (4/SIMD; needed for ds_read latency hiding --
// round-8 lesson: 4-wave/fatter-tile variant regressed to 27.6%).
// T2 swizzle: source col (idx&7)^(row&7), read slot (ks*4+fq)^(fr&7).
// T4 counted vmcnt: per-tile issue [A0 A1 | B0 B1 B2]; gates vmcnt(3)/vmcnt(2).
template <int OUT_BF16>
__global__ __launch_bounds__(512, 4) void gemm_bal(const u16* __restrict__ A,
                                                   const u16* __restrict__ B,
                                                   void* __restrict__ Cv,
                                                   int M, int N, int K) {
  (void)M;
  __shared__ __align__(16) u16 sA[2][128 * 64];   // 16 KiB per buf
  __shared__ __align__(16) u16 sB[2][192 * 64];   // 24 KiB per buf
  const int tid = threadIdx.x;                    // 0..511
  const int lane = tid & 63, w = tid >> 6;
  const int wm = w >> 2, wn = w & 3;              // wave grid 2M x 4N
  const int fr = lane & 15, fq = lane >> 4;
  const int r0 = blockIdx.x * 128, c0 = blockIdx.y * 192;

  const u16* aSrc[2];
  const u16* bSrc[3];
#pragma unroll
  for (int c = 0; c < 2; ++c) {
    const int idx = c * 512 + tid;
    const int row = idx >> 3;
    aSrc[c] = A + (size_t)(r0 + row) * K + ((idx & 7) ^ (row & 7)) * 8;
  }
#pragma unroll
  for (int c = 0; c < 3; ++c) {
    const int idx = c * 512 + tid;
    const int row = idx >> 3;
    bSrc[c] = B + (size_t)(c0 + row) * K + ((idx & 7) ^ (row & 7)) * 8;
  }

  const int sw0 = ((fq) ^ (fr & 7)) * 8;
  const int sw1 = ((4 + fq) ^ (fr & 7)) * 8;
  const int aB = (wm * 64 + fr) * 64;
  const int bB = (wn * 48 + fr) * 64;

  const f32x4 z4 = {0.f, 0.f, 0.f, 0.f};
  f32x4 acc[4][3];
#pragma unroll
  for (int m = 0; m < 4; ++m)
#pragma unroll
    for (int n = 0; n < 3; ++n) acc[m][n] = z4;

  const int NT = K >> 6;

#define SGA(c, buf, ko) gload16(&sA[buf][((c)*512 + w * 64) * 8], aSrc[c] + (ko))
#define SGB(c, buf, ko) gload16(&sB[buf][((c)*512 + w * 64) * 8], bSrc[c] + (ko))

  SGA(0, 0, 0); SGA(1, 0, 0);
  SGB(0, 0, 0); SGB(1, 0, 0); SGB(2, 0, 0);

  for (int u = 0; u < NT; ++u) {
    const int par = u & 1, nxt = par ^ 1;
    const u16* a = sA[par];
    const u16* b = sB[par];
    const bool pf = (u + 1 < NT);
    const size_t ko = (size_t)(u + 1) * 64;

    asm volatile("s_waitcnt vmcnt(3)" ::: "memory");
    __builtin_amdgcn_s_barrier();
    if (pf) { SGA(0, nxt, ko); SGA(1, nxt, ko); }

    if (pf) { asm volatile("s_waitcnt vmcnt(2)" ::: "memory"); }
    else    { asm volatile("s_waitcnt vmcnt(0)" ::: "memory"); }
    __builtin_amdgcn_s_barrier();
    bf16x8 bfr[3][2];
#pragma unroll
    for (int n = 0; n < 3; ++n) {
      bfr[n][0] = *(const bf16x8*)(b + bB + n * 1024 + sw0);
      bfr[n][1] = *(const bf16x8*)(b + bB + n * 1024 + sw1);
    }
    if (pf) { SGB(0, nxt, ko); SGB(1, nxt, ko); SGB(2, nxt, ko); }
    __builtin_amdgcn_s_barrier();
    __builtin_amdgcn_s_setprio(1);
#pragma unroll
    for (int mp = 0; mp < 2; ++mp) {
      bf16x8 afr[2][2];
#pragma unroll
      for (int i = 0; i < 2; ++i) {
        afr[i][0] = *(const bf16x8*)(a + aB + (2 * mp + i) * 1024 + sw0);
        afr[i][1] = *(const bf16x8*)(a + aB + (2 * mp + i) * 1024 + sw1);
      }
#pragma unroll
      for (int i = 0; i < 2; ++i)
#pragma unroll
        for (int n = 0; n < 3; ++n)
#pragma unroll
          for (int ks = 0; ks < 2; ++ks)
            acc[2 * mp + i][n] = __builtin_amdgcn_mfma_f32_16x16x32_bf16(
                afr[i][ks], bfr[n][ks], acc[2 * mp + i][n], 0, 0, 0);
    }
    __builtin_amdgcn_s_setprio(0);
  }
#undef SGA
#undef SGB

#pragma unroll
  for (int m = 0; m < 4; ++m) {
    const int gr = r0 + wm * 64 + m * 16 + fq * 4;
#pragma unroll
    for (int n = 0; n < 3; ++n) {
      const int gc = c0 + wn * 48 + n * 16 + fr;
#pragma unroll
      for (int j = 0; j < 4; ++j) {
        const size_t off = (size_t)(gr + j) * N + gc;
        if (OUT_BF16) ((u16*)Cv)[off] = f2bf(acc[m][n][j]);
        else          ((float*)Cv)[off] = acc[m][n][j];
      }
    }
  }
}

// ---------------------------------------------------------------- 3D RoPE (q,k) + K-frag emit
__global__ __launch_bounds__(256) void rope_kernel(u16* __restrict__ qkv,
                                                   const float* __restrict__ Rs,
                                                   u16* __restrict__ Kf) {
  const int bt = blockIdx.x;         // [0, 4096)
  const int b = bt >> 11;
  const int t = bt & 2047;
  const int tid = threadIdx.x;
  const float SC = 0.14724574f;      // (1/sqrt(96)) * log2(e)

  __shared__ __align__(16) u16 buf[3072];
  __shared__ __align__(16) float rbuf[288];

  u16* g = qkv + (size_t)bt * 4608;  // q at 0, k at 1536
#pragma unroll
  for (int r = 0; r < 2; ++r) {
    const int idx = r * 256 + tid;
    if (idx < 384)
      *reinterpret_cast<uint4*>(buf + idx * 8) = *reinterpret_cast<const uint4*>(g + idx * 8);
  }
  if (tid < 72)
    *reinterpret_cast<float4*>(rbuf + tid * 4) =
        *reinterpret_cast<const float4*>(Rs + (size_t)t * 288 + tid * 4);
  __syncthreads();

#pragma unroll
  for (int rep = 0; rep < 4; ++rep) {
    const int ft = rep * 256 + tid;          // [0,1024): qk = ft>>9, h=(ft&511)>>5, trip=ft&31
    const int base = (ft >> 9) * 1536 + ((ft & 511) >> 5) * 96 + (ft & 31) * 3;
    const float* R = rbuf + (ft & 31) * 9;
    const float x0 = bf2f(buf[base]), x1 = bf2f(buf[base + 1]), x2 = bf2f(buf[base + 2]);
    const float y0 = R[0] * x0 + R[1] * x1 + R[2] * x2;
    const float y1 = R[3] * x0 + R[4] * x1 + R[5] * x2;
    const float y2 = R[6] * x0 + R[7] * x1 + R[8] * x2;
    buf[base] = f2bf(y0); buf[base + 1] = f2bf(y1); buf[base + 2] = f2bf(y2);
  }
  __syncthreads();
  // q writeback (192 uint4)
  if (tid < 192)
    *reinterpret_cast<uint4*>(g + tid * 8) = *reinterpret_cast<const uint4*>(buf + tid * 8);
  // k -> Kf fragment scatter (192 uint4): tid = h*12 + r; c8 = r*8
  if (tid < 192) {
    const int h = tid / 12;
    const int r = tid % 12;
    const int kb = r >> 2, fq = r & 3;
    const int kt = t >> 6, m = (t >> 4) & 3, fr = t & 15;
    uint4 v = *reinterpret_cast<const uint4*>(buf + 1536 + h * 96 + r * 8);
    u16* p = reinterpret_cast<u16*>(&v);
#pragma unroll
    for (int e = 0; e < 8; ++e) p[e] = f2bf(bf2f(p[e]) * SC);
    const size_t dst = ((size_t)(b * 16 + h) * 32 + kt) * 6144 +
                       (size_t)((m * 3 + kb) * 64 + fq * 16 + fr) * 8;
    *reinterpret_cast<uint4*>(Kf + dst) = v;
  }
}

// ---------------------------------------------------------------- V fragment prep
__global__ __launch_bounds__(256) void vprep(const u16* __restrict__ qkv,
                                             u16* __restrict__ Vf) {
  const int kt = blockIdx.x, bh = blockIdx.y;
  const int b = bh >> 4, h = bh & 15;
  const int tid = threadIdx.x, lane = tid & 63, w = tid >> 6;
  __shared__ __align__(16) u16 vlds[64 * 96];

#pragma unroll
  for (int r = 0; r < 3; ++r) {
    const int idx = r * 256 + tid;
    const int kv = idx / 12, c8 = (idx % 12) * 8;
    gload16(vlds + (r * 256 + w * 64) * 8,
            qkv + (size_t)(b * 2048 + kt * 64 + kv) * 4608 + 3072 + h * 96 + c8);
  }
  __syncthreads();

  const size_t obase = ((size_t)bh * 32 + kt) * 6144;
#pragma unroll
  for (int r = 0; r < 3; ++r) {
    const int chunk = r * 256 + tid;
    const int sub = chunk >> 6, l = chunk & 63;
    const int n2 = sub >> 1, c = sub & 1;
    const int fr = l & 15, fq = l >> 4;
    const int d = n2 * 16 + fr;
    u16 out[8];
#pragma unroll
    for (int e = 0; e < 8; ++e) {
      const int kl = (c * 2 + (e >> 2)) * 16 + fq * 4 + (e & 3);
      out[e] = vlds[kl * 96 + d];
    }
    *reinterpret_cast<uint4*>(Vf + obase + (size_t)chunk * 8) =
        *reinterpret_cast<uint4*>(out);
  }
}

// ---------------------------------------------------------------- flash attention
// Block = 128 Q-rows, 4 waves x 32 rows. Swapped QK^T; ones-column denominator;
// T13 defer-max (THR=8, exp2 domain).
// Makespan-balanced qt map: grid = 512 blocks = exactly 2/CU (all co-resident,
// no backfill) -> CU makespan = sum of its two blocks' work. Linear block->CU
// round-robin (period 256) pairs blockIdx.y with y+8; map qt so pairs sum to
// 15: work = 2(qt1+qt2)+4 = 34 uniform (old 15-y map gave 20..48, 2.4x skew).
__global__ __launch_bounds__(256, 2) void attn_fwd(const u16* __restrict__ qkvb,
                                                   const u16* __restrict__ Kf,
                                                   const u16* __restrict__ Vf,
                                                   u16* __restrict__ y) {
  const int bh = blockIdx.x;
  const int yy = (int)blockIdx.y;
  const int qt = (yy < 8) ? (15 - yy) : (yy - 8);  // co-resident pair sums to 15
  const int b = bh >> 4, h = bh & 15;
  const int tid = threadIdx.x, lane = tid & 63, w = tid >> 6;
  const int fr = lane & 15, fq = lane >> 4;
  const int q0 = qt * 128;
  const int qw = q0 + w * 32;            // wave's first q row

  __shared__ __align__(16) u16 kbl[2][6144];
  __shared__ __align__(16) u16 vbl[2][6144];

  bf16x8 qf[2][3];
#pragma unroll
  for (int nq = 0; nq < 2; ++nq)
#pragma unroll
    for (int kb = 0; kb < 3; ++kb)
      qf[nq][kb] = *reinterpret_cast<const bf16x8*>(
          qkvb + (size_t)(b * 2048 + qw + nq * 16 + fr) * 4608 + h * 96 + kb * 32 + fq * 8);

  union OneU { u16 s[8]; bf16x8 v; };
  OneU ou;
#pragma unroll
  for (int e = 0; e < 8; ++e) ou.s[e] = 0x3f80;  // bf16 1.0
  const bf16x8 vones = ou.v;

  const f32x4 z4 = {0.f, 0.f, 0.f, 0.f};
  f32x4 oacc[2][7];                      // [..][6] = ones-column denominator
#pragma unroll
  for (int mq = 0; mq < 2; ++mq)
#pragma unroll
    for (int n2 = 0; n2 < 7; ++n2) oacc[mq][n2] = z4;
  float mrow[2] = {-1e30f, -1e30f};

  const int nt = 2 * qt + 2;
  const size_t tb = (size_t)bh * 32 * 6144;

#define STAGE(buf, kt_)                                                         \
  do {                                                                          \
    const size_t sb = tb + (size_t)(kt_)*6144;                                  \
    _Pragma("unroll") for (int r = 0; r < 3; ++r) {                             \
      gload16(kbl[buf] + (r * 256 + w * 64) * 8, Kf + sb + (r * 256 + w * 64 + lane) * 8); \
      gload16(vbl[buf] + (r * 256 + w * 64) * 8, Vf + sb + (r * 256 + w * 64 + lane) * 8); \
    }                                                                           \
  } while (0)

  STAGE(0, 0);
  for (int kt = 0; kt < nt; ++kt) {
    __syncthreads();                     // stage(kt) landed; compute(kt-1) done
    if (kt + 1 < nt) STAGE((kt + 1) & 1, kt + 1);
    const u16* kc = kbl[kt & 1];
    const u16* vc = vbl[kt & 1];
    const int k0 = kt * 64;

    if (k0 <= qw + 31) {                 // wave has unmasked work (wave-uniform)
      // ---- S^T = K Q (log2 domain; K pre-scaled)
      f32x4 sacc[4][2];
#pragma unroll
      for (int m = 0; m < 4; ++m)
#pragma unroll
        for (int nq = 0; nq < 2; ++nq) sacc[m][nq] = z4;
#pragma unroll
      for (int kb = 0; kb < 3; ++kb)
#pragma unroll
        for (int m = 0; m < 4; ++m) {
          const bf16x8 kfrag = *reinterpret_cast<const bf16x8*>(kc + ((m * 3 + kb) * 64 + lane) * 8);
#pragma unroll
          for (int nq = 0; nq < 2; ++nq)
            sacc[m][nq] = __builtin_amdgcn_mfma_f32_16x16x32_bf16(kfrag, qf[nq][kb], sacc[m][nq], 0, 0, 0);
        }
      if (k0 + 63 > qw) {                // diagonal: mask kpos > qpos
#pragma unroll
        for (int m = 0; m < 4; ++m) {
          const int kpos = k0 + m * 16 + fq * 4;
#pragma unroll
          for (int nq = 0; nq < 2; ++nq) {
            const int qpos = qw + nq * 16 + fr;
#pragma unroll
            for (int j = 0; j < 4; ++j)
              if (kpos + j > qpos) sacc[m][nq][j] = -1e30f;
          }
        }
      }
      // ---- row max via max3 tree + cross-group reduce
      float mx[2];
#pragma unroll
      for (int nq = 0; nq < 2; ++nq) {
        const float t0 = max3f(sacc[0][nq][0], sacc[0][nq][1], sacc[0][nq][2]);
        const float t1 = max3f(sacc[0][nq][3], sacc[1][nq][0], sacc[1][nq][1]);
        const float t2 = max3f(sacc[1][nq][2], sacc[1][nq][3], sacc[2][nq][0]);
        const float t3 = max3f(sacc[2][nq][1], sacc[2][nq][2], sacc[2][nq][3]);
        const float t4 = max3f(sacc[3][nq][0], sacc[3][nq][1], sacc[3][nq][2]);
        float m = max3f(max3f(t0, t1, t2), t3, max3f(t4, sacc[3][nq][3], t0));
        m = fmaxf(m, __shfl_xor(m, 16));
        m = fmaxf(m, __shfl_xor(m, 32));
        mx[nq] = m;
      }
      // ---- T13 defer-max: rescale only when max grew > THR (wave-uniform)
      const bool need = (mx[0] - mrow[0] > 8.0f) || (mx[1] - mrow[1] > 8.0f);
      if (__any(need)) {
        float al[2];
#pragma unroll
        for (int nq = 0; nq < 2; ++nq) {
          const float mn = fmaxf(mrow[nq], mx[nq]);
          al[nq] = exp2f_fast(mrow[nq] - mn);
          mrow[nq] = mn;
        }
        float alb[2][4];
#pragma unroll
        for (int mq = 0; mq < 2; ++mq)
#pragma unroll
          for (int j = 0; j < 4; ++j) alb[mq][j] = __shfl(al[mq], fq * 4 + j);
#pragma unroll
        for (int mq = 0; mq < 2; ++mq)
#pragma unroll
          for (int n2 = 0; n2 < 7; ++n2) {
            f32x4 t = oacc[mq][n2];
            t[0] *= alb[mq][0]; t[1] *= alb[mq][1]; t[2] *= alb[mq][2]; t[3] *= alb[mq][3];
            oacc[mq][n2] = t;
          }
      }
      // ---- P = exp2(S - mrow)
#pragma unroll
      for (int nq = 0; nq < 2; ++nq)
#pragma unroll
        for (int m = 0; m < 4; ++m) {
          f32x4 p;
#pragma unroll
          for (int j = 0; j < 4; ++j) p[j] = exp2f_fast(sacc[m][nq][j] - mrow[nq]);
          sacc[m][nq] = p;
        }
      // ---- pack P from registers (k-permutation matches Vf layout)
      union PB { u32 u[4]; bf16x8 v; };
      PB pa[2][2];
#pragma unroll
      for (int c = 0; c < 2; ++c)
#pragma unroll
        for (int mq = 0; mq < 2; ++mq) {
          pa[c][mq].u[0] = cvtpk(sacc[2 * c][mq][0], sacc[2 * c][mq][1]);
          pa[c][mq].u[1] = cvtpk(sacc[2 * c][mq][2], sacc[2 * c][mq][3]);
          pa[c][mq].u[2] = cvtpk(sacc[2 * c + 1][mq][0], sacc[2 * c + 1][mq][1]);
          pa[c][mq].u[3] = cvtpk(sacc[2 * c + 1][mq][2], sacc[2 * c + 1][mq][3]);
        }
      // ---- O += P V  (n2==6: ones column accumulates the denominator)
#pragma unroll
      for (int c = 0; c < 2; ++c)
#pragma unroll
        for (int n2 = 0; n2 < 7; ++n2) {
          const bf16x8 vfrag = (n2 < 6)
              ? *reinterpret_cast<const bf16x8*>(vc + ((n2 * 2 + c) * 64 + lane) * 8)
              : vones;
#pragma unroll
          for (int mq = 0; mq < 2; ++mq)
            oacc[mq][n2] = __builtin_amdgcn_mfma_f32_16x16x32_bf16(pa[c][mq].v, vfrag, oacc[mq][n2], 0, 0, 0);
        }
    }
  }
#undef STAGE

  // ---- epilogue: denominator lives in oacc[mq][6][j] (lane-local, no shfl)
  float inv[2][4];
#pragma unroll
  for (int mq = 0; mq < 2; ++mq)
#pragma unroll
    for (int j = 0; j < 4; ++j)
      inv[mq][j] = __builtin_amdgcn_rcpf(oacc[mq][6][j]);
#pragma unroll
  for (int mq = 0; mq < 2; ++mq)
#pragma unroll
    for (int n2 = 0; n2 < 6; ++n2)
#pragma unroll
      for (int j = 0; j < 4; ++j) {
        const size_t off =
            (size_t)(b * 2048 + qw + mq * 16 + fq * 4 + j) * 1536 + h * 96 + n2 * 16 + fr;
        y[off] = f2bf(oacc[mq][n2][j] * inv[mq][j]);
      }
}

// ---------------------------------------------------------------- launch
extern "C" void kernel_launch(void* const* d_in, const int* in_sizes, int n_in,
                              void* d_out, int out_size, void* d_ws, size_t ws_size,
                              hipStream_t stream) {
  (void)in_sizes; (void)n_in; (void)out_size; (void)ws_size;
  const float* x     = (const float*)d_in[0];
  const float* w_qkv = (const float*)d_in[1];
  const float* w_o   = (const float*)d_in[2];
  const float* Rs    = (const float*)d_in[3];
  float* out = (float*)d_out;

  // ws layout (u16 elems). Kf/Vf alias xb/wqkvb (dead after gemm1). Total 81.8 MB.
  u16* xb    = (u16*)d_ws;            // 6291456
  u16* wqkvb = xb + 6291456;          // 7077888
  u16* wob   = xb + 13369344;         // 2359296
  u16* qkvb  = xb + 15728640;         // 18874368
  u16* yb    = xb + 34603008;         // 6291456
  u16* Kf    = xb;                    // 6291456 (32 bh x 32 kt x 6144)
  u16* Vf    = xb + 6291456;          // 6291456

  cvt3<<<(1572864 + 1769472 + 589824) / 256, 256, 0, stream>>>(
      x, xb, 1572864, w_qkv, wqkvb, 1769472, w_o, wob, 589824);

  gemm_bal<1><<<dim3(32, 24), 512, 0, stream>>>(xb, wqkvb, (void*)qkvb, 4096, 4608, 1536);
  rope_kernel<<<4096, 256, 0, stream>>>(qkvb, Rs, Kf);
  vprep<<<dim3(32, 32), 256, 0, stream>>>(qkvb, Vf);
  attn_fwd<<<dim3(32, 16), 256, 0, stream>>>(qkvb, Kf, Vf, yb);
  gemm_bal<0><<<dim3(32, 8), 512, 0, stream>>>(yb, wob, (void*)out, 4096, 1536, 1536);
}

// Round 12
// 270.149 us; speedup vs baseline: 1.0199x; 1.0199x over previous
//
#include <hip/hip_runtime.h>
#include <stdint.h>

// B=2, T=2048, D_MODEL=1536, H=16, hd=96, n_trip=32. qkv row = 4608, rows = 4096.

typedef unsigned short u16;
typedef unsigned int u32;
typedef __attribute__((ext_vector_type(8))) __bf16 bf16x8;   // MFMA A/B frag
typedef __attribute__((ext_vector_type(4))) float f32x4;     // MFMA C/D frag

#define DEV static __device__ __forceinline__

DEV u16 f2bf(float f) {
  u32 u = __float_as_uint(f);
  return (u16)((u + 0x7fffu + ((u >> 16) & 1u)) >> 16);  // RNE
}
DEV float bf2f(u16 h) { return __uint_as_float(((u32)h) << 16); }
DEV u32 cvtpk(float lo, float hi) {  // packed f32->bf16 pair (lo->bits[15:0])
  u32 r;
  asm("v_cvt_pk_bf16_f32 %0, %1, %2" : "=v"(r) : "v"(lo), "v"(hi));
  return r;
}
DEV float exp2f_fast(float x) {
  float r;
  asm("v_exp_f32 %0, %1" : "=v"(r) : "v"(x));
  return r;
}
DEV float max3f(float a, float b, float c) { return fmaxf(fmaxf(a, b), c); }

// async global->LDS, 16B/lane. LDS dest = wave-uniform base + lane*16.
DEV void gload16(u16* lds_dst, const u16* gsrc) {
  __builtin_amdgcn_global_load_lds(
      (const __attribute__((address_space(1))) void*)gsrc,
      (__attribute__((address_space(3))) void*)lds_dst, 16, 0, 0);
}

// ---------------------------------------------------------------- cvt f32->bf16 x3
__global__ __launch_bounds__(256) void cvt3(const float* __restrict__ a, u16* __restrict__ ao, int na4,
                                            const float* __restrict__ b, u16* __restrict__ bo, int nb4,
                                            const float* __restrict__ c, u16* __restrict__ co, int nc4) {
  int i = blockIdx.x * 256 + threadIdx.x;
  const float* src;
  u16* dst;
  if (i < na4) { src = a; dst = ao; }
  else if (i < na4 + nb4) { i -= na4; src = b; dst = bo; }
  else if (i < na4 + nb4 + nc4) { i -= na4 + nb4; src = c; dst = co; }
  else return;
  float4 v = reinterpret_cast<const float4*>(src)[i];
  ushort4 o;
  o.x = f2bf(v.x); o.y = f2bf(v.y); o.z = f2bf(v.z); o.w = f2bf(v.w);
  reinterpret_cast<ushort4*>(dst)[i] = o;
}

// ---------------------------------------------------------------- GEMM (128x192)
// VERIFIED config (66.5 us, MfmaUtil 35%, VGPR 56): BM=128, BN=192, BK=64,
// 8 waves (512 thr) as 2M x 4N -> wave tile 64x48. LDS 80 KiB dbuf -> 2
// blocks/CU = 16 waves/CU (4/SIMD; needed for ds_read latency hiding --
// round-8 lesson: 4-wave/fatter-tile variant regressed to 27.6%).
// T2 swizzle: source col (idx&7)^(row&7), read slot (ks*4+fq)^(fr&7).
// T4 counted vmcnt: per-tile issue [A0 A1 | B0 B1 B2]; gates vmcnt(3)/vmcnt(2).
template <int OUT_BF16>
__global__ __launch_bounds__(512, 4) void gemm_bal(const u16* __restrict__ A,
                                                   const u16* __restrict__ B,
                                                   void* __restrict__ Cv,
                                                   int M, int N, int K) {
  (void)M;
  __shared__ __align__(16) u16 sA[2][128 * 64];   // 16 KiB per buf
  __shared__ __align__(16) u16 sB[2][192 * 64];   // 24 KiB per buf
  const int tid = threadIdx.x;                    // 0..511
  const int lane = tid & 63, w = tid >> 6;
  const int wm = w >> 2, wn = w & 3;              // wave grid 2M x 4N
  const int fr = lane & 15, fq = lane >> 4;
  const int r0 = blockIdx.x * 128, c0 = blockIdx.y * 192;

  const u16* aSrc[2];
  const u16* bSrc[3];
#pragma unroll
  for (int c = 0; c < 2; ++c) {
    const int idx = c * 512 + tid;
    const int row = idx >> 3;
    aSrc[c] = A + (size_t)(r0 + row) * K + ((idx & 7) ^ (row & 7)) * 8;
  }
#pragma unroll
  for (int c = 0; c < 3; ++c) {
    const int idx = c * 512 + tid;
    const int row = idx >> 3;
    bSrc[c] = B + (size_t)(c0 + row) * K + ((idx & 7) ^ (row & 7)) * 8;
  }

  const int sw0 = ((fq) ^ (fr & 7)) * 8;
  const int sw1 = ((4 + fq) ^ (fr & 7)) * 8;
  const int aB = (wm * 64 + fr) * 64;
  const int bB = (wn * 48 + fr) * 64;

  const f32x4 z4 = {0.f, 0.f, 0.f, 0.f};
  f32x4 acc[4][3];
#pragma unroll
  for (int m = 0; m < 4; ++m)
#pragma unroll
    for (int n = 0; n < 3; ++n) acc[m][n] = z4;

  const int NT = K >> 6;

#define SGA(c, buf, ko) gload16(&sA[buf][((c)*512 + w * 64) * 8], aSrc[c] + (ko))
#define SGB(c, buf, ko) gload16(&sB[buf][((c)*512 + w * 64) * 8], bSrc[c] + (ko))

  SGA(0, 0, 0); SGA(1, 0, 0);
  SGB(0, 0, 0); SGB(1, 0, 0); SGB(2, 0, 0);

  for (int u = 0; u < NT; ++u) {
    const int par = u & 1, nxt = par ^ 1;
    const u16* a = sA[par];
    const u16* b = sB[par];
    const bool pf = (u + 1 < NT);
    const size_t ko = (size_t)(u + 1) * 64;

    asm volatile("s_waitcnt vmcnt(3)" ::: "memory");
    __builtin_amdgcn_s_barrier();
    if (pf) { SGA(0, nxt, ko); SGA(1, nxt, ko); }

    if (pf) { asm volatile("s_waitcnt vmcnt(2)" ::: "memory"); }
    else    { asm volatile("s_waitcnt vmcnt(0)" ::: "memory"); }
    __builtin_amdgcn_s_barrier();
    bf16x8 bfr[3][2];
#pragma unroll
    for (int n = 0; n < 3; ++n) {
      bfr[n][0] = *(const bf16x8*)(b + bB + n * 1024 + sw0);
      bfr[n][1] = *(const bf16x8*)(b + bB + n * 1024 + sw1);
    }
    if (pf) { SGB(0, nxt, ko); SGB(1, nxt, ko); SGB(2, nxt, ko); }
    __builtin_amdgcn_s_barrier();
    __builtin_amdgcn_s_setprio(1);
#pragma unroll
    for (int mp = 0; mp < 2; ++mp) {
      bf16x8 afr[2][2];
#pragma unroll
      for (int i = 0; i < 2; ++i) {
        afr[i][0] = *(const bf16x8*)(a + aB + (2 * mp + i) * 1024 + sw0);
        afr[i][1] = *(const bf16x8*)(a + aB + (2 * mp + i) * 1024 + sw1);
      }
#pragma unroll
      for (int i = 0; i < 2; ++i)
#pragma unroll
        for (int n = 0; n < 3; ++n)
#pragma unroll
          for (int ks = 0; ks < 2; ++ks)
            acc[2 * mp + i][n] = __builtin_amdgcn_mfma_f32_16x16x32_bf16(
                afr[i][ks], bfr[n][ks], acc[2 * mp + i][n], 0, 0, 0);
    }
    __builtin_amdgcn_s_setprio(0);
  }
#undef SGA
#undef SGB

#pragma unroll
  for (int m = 0; m < 4; ++m) {
    const int gr = r0 + wm * 64 + m * 16 + fq * 4;
#pragma unroll
    for (int n = 0; n < 3; ++n) {
      const int gc = c0 + wn * 48 + n * 16 + fr;
#pragma unroll
      for (int j = 0; j < 4; ++j) {
        const size_t off = (size_t)(gr + j) * N + gc;
        if (OUT_BF16) ((u16*)Cv)[off] = f2bf(acc[m][n][j]);
        else          ((float*)Cv)[off] = acc[m][n][j];
      }
    }
  }
}

// ---------------------------------------------------------------- 3D RoPE (q,k) + K-frag emit
__global__ __launch_bounds__(256) void rope_kernel(u16* __restrict__ qkv,
                                                   const float* __restrict__ Rs,
                                                   u16* __restrict__ Kf) {
  const int bt = blockIdx.x;         // [0, 4096)
  const int b = bt >> 11;
  const int t = bt & 2047;
  const int tid = threadIdx.x;
  const float SC = 0.14724574f;      // (1/sqrt(96)) * log2(e)

  __shared__ __align__(16) u16 buf[3072];
  __shared__ __align__(16) float rbuf[288];

  u16* g = qkv + (size_t)bt * 4608;  // q at 0, k at 1536
#pragma unroll
  for (int r = 0; r < 2; ++r) {
    const int idx = r * 256 + tid;
    if (idx < 384)
      *reinterpret_cast<uint4*>(buf + idx * 8) = *reinterpret_cast<const uint4*>(g + idx * 8);
  }
  if (tid < 72)
    *reinterpret_cast<float4*>(rbuf + tid * 4) =
        *reinterpret_cast<const float4*>(Rs + (size_t)t * 288 + tid * 4);
  __syncthreads();

#pragma unroll
  for (int rep = 0; rep < 4; ++rep) {
    const int ft = rep * 256 + tid;          // [0,1024): qk = ft>>9, h=(ft&511)>>5, trip=ft&31
    const int base = (ft >> 9) * 1536 + ((ft & 511) >> 5) * 96 + (ft & 31) * 3;
    const float* R = rbuf + (ft & 31) * 9;
    const float x0 = bf2f(buf[base]), x1 = bf2f(buf[base + 1]), x2 = bf2f(buf[base + 2]);
    const float y0 = R[0] * x0 + R[1] * x1 + R[2] * x2;
    const float y1 = R[3] * x0 + R[4] * x1 + R[5] * x2;
    const float y2 = R[6] * x0 + R[7] * x1 + R[8] * x2;
    buf[base] = f2bf(y0); buf[base + 1] = f2bf(y1); buf[base + 2] = f2bf(y2);
  }
  __syncthreads();
  // q writeback (192 uint4)
  if (tid < 192)
    *reinterpret_cast<uint4*>(g + tid * 8) = *reinterpret_cast<const uint4*>(buf + tid * 8);
  // k -> Kf fragment scatter (192 uint4): tid = h*12 + r; c8 = r*8
  if (tid < 192) {
    const int h = tid / 12;
    const int r = tid % 12;
    const int kb = r >> 2, fq = r & 3;
    const int kt = t >> 6, m = (t >> 4) & 3, fr = t & 15;
    uint4 v = *reinterpret_cast<const uint4*>(buf + 1536 + h * 96 + r * 8);
    u16* p = reinterpret_cast<u16*>(&v);
#pragma unroll
    for (int e = 0; e < 8; ++e) p[e] = f2bf(bf2f(p[e]) * SC);
    const size_t dst = ((size_t)(b * 16 + h) * 32 + kt) * 6144 +
                       (size_t)((m * 3 + kb) * 64 + fq * 16 + fr) * 8;
    *reinterpret_cast<uint4*>(Kf + dst) = v;
  }
}

// ---------------------------------------------------------------- V fragment prep
__global__ __launch_bounds__(256) void vprep(const u16* __restrict__ qkv,
                                             u16* __restrict__ Vf) {
  const int kt = blockIdx.x, bh = blockIdx.y;
  const int b = bh >> 4, h = bh & 15;
  const int tid = threadIdx.x, lane = tid & 63, w = tid >> 6;
  __shared__ __align__(16) u16 vlds[64 * 96];

#pragma unroll
  for (int r = 0; r < 3; ++r) {
    const int idx = r * 256 + tid;
    const int kv = idx / 12, c8 = (idx % 12) * 8;
    gload16(vlds + (r * 256 + w * 64) * 8,
            qkv + (size_t)(b * 2048 + kt * 64 + kv) * 4608 + 3072 + h * 96 + c8);
  }
  __syncthreads();

  const size_t obase = ((size_t)bh * 32 + kt) * 6144;
#pragma unroll
  for (int r = 0; r < 3; ++r) {
    const int chunk = r * 256 + tid;
    const int sub = chunk >> 6, l = chunk & 63;
    const int n2 = sub >> 1, c = sub & 1;
    const int fr = l & 15, fq = l >> 4;
    const int d = n2 * 16 + fr;
    u16 out[8];
#pragma unroll
    for (int e = 0; e < 8; ++e) {
      const int kl = (c * 2 + (e >> 2)) * 16 + fq * 4 + (e & 3);
      out[e] = vlds[kl * 96 + d];
    }
    *reinterpret_cast<uint4*>(Vf + obase + (size_t)chunk * 8) =
        *reinterpret_cast<uint4*>(out);
  }
}

// ---------------------------------------------------------------- flash attention
// Block = 64 Q-rows, 4 waves x 16 rows; grid = 32 bh x 32 qt = 1024 blocks at
// 3 blocks/CU (LDS 48 KiB x3 = 144 KiB) -> 1024 blocks on 768 slots gives real
// BACKFILL (round-11 lesson: dispatch-order remapping at grid==slots was
// neutral; only grid >> slots lets the scheduler balance causal skew). LPT
// order (heavy qt first). Per-tile math identical: swapped QK^T, ones-column
// denominator, T13 defer-max (THR=8, exp2 domain).
__global__ __launch_bounds__(256, 3) void attn_fwd(const u16* __restrict__ qkvb,
                                                   const u16* __restrict__ Kf,
                                                   const u16* __restrict__ Vf,
                                                   u16* __restrict__ y) {
  const int bh = blockIdx.x;
  const int qt = 31 - (int)blockIdx.y;   // LPT: heavy blocks dispatched first
  const int b = bh >> 4, h = bh & 15;
  const int tid = threadIdx.x, lane = tid & 63, w = tid >> 6;
  const int fr = lane & 15, fq = lane >> 4;
  const int q0 = qt * 64;
  const int qw = q0 + w * 16;            // wave's 16 q rows

  __shared__ __align__(16) u16 kbl[2][6144];
  __shared__ __align__(16) u16 vbl[2][6144];

  bf16x8 qf[3];
#pragma unroll
  for (int kb = 0; kb < 3; ++kb)
    qf[kb] = *reinterpret_cast<const bf16x8*>(
        qkvb + (size_t)(b * 2048 + qw + fr) * 4608 + h * 96 + kb * 32 + fq * 8);

  union OneU { u16 s[8]; bf16x8 v; };
  OneU ou;
#pragma unroll
  for (int e = 0; e < 8; ++e) ou.s[e] = 0x3f80;  // bf16 1.0
  const bf16x8 vones = ou.v;

  const f32x4 z4 = {0.f, 0.f, 0.f, 0.f};
  f32x4 oacc[7];                         // [6] = ones-column denominator
#pragma unroll
  for (int n2 = 0; n2 < 7; ++n2) oacc[n2] = z4;
  float mrow = -1e30f;

  const int nt = qt + 1;
  const size_t tb = (size_t)bh * 32 * 6144;

#define STAGE(buf, kt_)                                                         \
  do {                                                                          \
    const size_t sb = tb + (size_t)(kt_)*6144;                                  \
    _Pragma("unroll") for (int r = 0; r < 3; ++r) {                             \
      gload16(kbl[buf] + (r * 256 + w * 64) * 8, Kf + sb + (r * 256 + w * 64 + lane) * 8); \
      gload16(vbl[buf] + (r * 256 + w * 64) * 8, Vf + sb + (r * 256 + w * 64 + lane) * 8); \
    }                                                                           \
  } while (0)

  STAGE(0, 0);
  for (int kt = 0; kt < nt; ++kt) {
    __syncthreads();                     // stage(kt) landed; compute(kt-1) done
    if (kt + 1 < nt) STAGE((kt + 1) & 1, kt + 1);
    const u16* kc = kbl[kt & 1];
    const u16* vc = vbl[kt & 1];
    const int k0 = kt * 64;

    if (k0 <= qw + 15) {                 // wave has unmasked work (wave-uniform)
      // ---- S^T = K Q (log2 domain; K pre-scaled): sacc[m][j] = S[k0+m*16+fq*4+j][qw+fr]
      f32x4 sacc[4];
#pragma unroll
      for (int m = 0; m < 4; ++m) sacc[m] = z4;
#pragma unroll
      for (int kb = 0; kb < 3; ++kb)
#pragma unroll
        for (int m = 0; m < 4; ++m) {
          const bf16x8 kfrag = *reinterpret_cast<const bf16x8*>(kc + ((m * 3 + kb) * 64 + lane) * 8);
          sacc[m] = __builtin_amdgcn_mfma_f32_16x16x32_bf16(kfrag, qf[kb], sacc[m], 0, 0, 0);
        }
      if (k0 + 63 > qw) {                // diagonal: mask kpos > qpos
#pragma unroll
        for (int m = 0; m < 4; ++m) {
          const int kpos = k0 + m * 16 + fq * 4;
          const int qpos = qw + fr;
#pragma unroll
          for (int j = 0; j < 4; ++j)
            if (kpos + j > qpos) sacc[m][j] = -1e30f;
        }
      }
      // ---- row max via max3 tree + cross-group reduce (row = q = fr)
      const float t0 = max3f(sacc[0][0], sacc[0][1], sacc[0][2]);
      const float t1 = max3f(sacc[0][3], sacc[1][0], sacc[1][1]);
      const float t2 = max3f(sacc[1][2], sacc[1][3], sacc[2][0]);
      const float t3 = max3f(sacc[2][1], sacc[2][2], sacc[2][3]);
      const float t4 = max3f(sacc[3][0], sacc[3][1], sacc[3][2]);
      float mx = max3f(max3f(t0, t1, t2), t3, max3f(t4, sacc[3][3], t0));
      mx = fmaxf(mx, __shfl_xor(mx, 16));
      mx = fmaxf(mx, __shfl_xor(mx, 32));
      // ---- T13 defer-max: rescale only when max grew > THR (wave-uniform)
      if (__any(mx - mrow > 8.0f)) {
        const float mn = fmaxf(mrow, mx);
        const float al = exp2f_fast(mrow - mn);
        mrow = mn;
        float alb[4];
#pragma unroll
        for (int j = 0; j < 4; ++j) alb[j] = __shfl(al, fq * 4 + j);
#pragma unroll
        for (int n2 = 0; n2 < 7; ++n2) {
          f32x4 t = oacc[n2];
          t[0] *= alb[0]; t[1] *= alb[1]; t[2] *= alb[2]; t[3] *= alb[3];
          oacc[n2] = t;
        }
      }
      // ---- P = exp2(S - mrow)
#pragma unroll
      for (int m = 0; m < 4; ++m) {
        f32x4 p;
#pragma unroll
        for (int j = 0; j < 4; ++j) p[j] = exp2f_fast(sacc[m][j] - mrow);
        sacc[m] = p;
      }
      // ---- pack P from registers (k-permutation matches Vf layout)
      union PB { u32 u[4]; bf16x8 v; };
      PB pa[2];
#pragma unroll
      for (int c = 0; c < 2; ++c) {
        pa[c].u[0] = cvtpk(sacc[2 * c][0], sacc[2 * c][1]);
        pa[c].u[1] = cvtpk(sacc[2 * c][2], sacc[2 * c][3]);
        pa[c].u[2] = cvtpk(sacc[2 * c + 1][0], sacc[2 * c + 1][1]);
        pa[c].u[3] = cvtpk(sacc[2 * c + 1][2], sacc[2 * c + 1][3]);
      }
      // ---- O += P V  (n2==6: ones column accumulates the denominator)
#pragma unroll
      for (int c = 0; c < 2; ++c)
#pragma unroll
        for (int n2 = 0; n2 < 7; ++n2) {
          const bf16x8 vfrag = (n2 < 6)
              ? *reinterpret_cast<const bf16x8*>(vc + ((n2 * 2 + c) * 64 + lane) * 8)
              : vones;
          oacc[n2] = __builtin_amdgcn_mfma_f32_16x16x32_bf16(pa[c].v, vfrag, oacc[n2], 0, 0, 0);
        }
    }
  }
#undef STAGE

  // ---- epilogue: O row = qw + fq*4 + j; denominator in oacc[6][j] (lane-local)
  float inv[4];
#pragma unroll
  for (int j = 0; j < 4; ++j) inv[j] = __builtin_amdgcn_rcpf(oacc[6][j]);
#pragma unroll
  for (int n2 = 0; n2 < 6; ++n2)
#pragma unroll
    for (int j = 0; j < 4; ++j) {
      const size_t off =
          (size_t)(b * 2048 + qw + fq * 4 + j) * 1536 + h * 96 + n2 * 16 + fr;
      y[off] = f2bf(oacc[n2][j] * inv[j]);
    }
}

// ---------------------------------------------------------------- launch
extern "C" void kernel_launch(void* const* d_in, const int* in_sizes, int n_in,
                              void* d_out, int out_size, void* d_ws, size_t ws_size,
                              hipStream_t stream) {
  (void)in_sizes; (void)n_in; (void)out_size; (void)ws_size;
  const float* x     = (const float*)d_in[0];
  const float* w_qkv = (const float*)d_in[1];
  const float* w_o   = (const float*)d_in[2];
  const float* Rs    = (const float*)d_in[3];
  float* out = (float*)d_out;

  // ws layout (u16 elems). Kf/Vf alias xb/wqkvb (dead after gemm1). Total 81.8 MB.
  u16* xb    = (u16*)d_ws;            // 6291456
  u16* wqkvb = xb + 6291456;          // 7077888
  u16* wob   = xb + 13369344;         // 2359296
  u16* qkvb  = xb + 15728640;         // 18874368
  u16* yb    = xb + 34603008;         // 6291456
  u16* Kf    = xb;                    // 6291456 (32 bh x 32 kt x 6144)
  u16* Vf    = xb + 6291456;          // 6291456

  cvt3<<<(1572864 + 1769472 + 589824) / 256, 256, 0, stream>>>(
      x, xb, 1572864, w_qkv, wqkvb, 1769472, w_o, wob, 589824);

  gemm_bal<1><<<dim3(32, 24), 512, 0, stream>>>(xb, wqkvb, (void*)qkvb, 4096, 4608, 1536);
  rope_kernel<<<4096, 256, 0, stream>>>(qkvb, Rs, Kf);
  vprep<<<dim3(32, 32), 256, 0, stream>>>(qkvb, Vf);
  attn_fwd<<<dim3(32, 32), 256, 0, stream>>>(qkvb, Kf, Vf, yb);
  gemm_bal<0><<<dim3(32, 8), 512, 0, stream>>>(yb, wob, (void*)out, 4096, 1536, 1536);
}